// Round 20
// baseline (787.598 us; speedup 1.0000x reference)
//
#include <hip/hip_runtime.h>
#include <hip/hip_bf16.h>

#define NN 100000
#define NE 3200000
#define NB 512
#define BINW 128                  // nodes per bin (bin = node >> 7)
#define NBINS 782                 // ceil(NN / 128); 782*128 = 100096
#define EPB 8192                  // edges per p1/p3 block
#define NBLK 391                  // ceil(NE / EPB)
#define PK 6272                   // pool k-chunk (r16-proven best: 16*6272 = 100352 >= NN)
#define PNK 16

typedef unsigned short ushort_t;
typedef unsigned int uint_t;
typedef unsigned char uchar_t;
typedef __attribute__((ext_vector_type(8))) short short8v;   // 8 bf16 (4 VGPRs)
typedef __attribute__((ext_vector_type(4))) float f32x4v;

static __device__ __forceinline__ short f2bf(float f) {
    __hip_bfloat16 h = __float2bfloat16(f);
    return *reinterpret_cast<short*>(&h);
}
static __device__ __forceinline__ float bf2f(ushort_t u) {
    return __uint_as_float(((uint_t)u) << 16);
}

// ---------------- p1: per-block bin-histograms (dst AND src), BOTH graphs ----------------
__global__ __launch_bounds__(256) void k_p1(const int* __restrict__ srcA,
                                            const int* __restrict__ dstA,
                                            const int* __restrict__ srcB,
                                            const int* __restrict__ dstB,
                                            int* __restrict__ cnt4,
                                            int* __restrict__ binTot) {
    __shared__ int hD[NBINS], hS[NBINS];
    int t = threadIdx.x, b = blockIdx.x;
    int g = (b >= NBLK) ? 1 : 0;
    int bb = b - g * NBLK;
    const int* src = g ? srcB : srcA;
    const int* dst = g ? dstB : dstA;
    int* cntD = cnt4 + (size_t)(2 * g)     * NBLK * NBINS;
    int* cntS = cnt4 + (size_t)(2 * g + 1) * NBLK * NBINS;
    int* btD  = binTot + (2 * g) * NBINS;
    int* btS  = binTot + (2 * g + 1) * NBINS;
    for (int i = t; i < NBINS; i += 256) { hD[i] = 0; hS[i] = 0; }
    __syncthreads();
    int base = bb * EPB;
#pragma unroll
    for (int i = 0; i < EPB / 1024; i++) {
        int idx = base + i * 1024 + t * 4;
        if (idx < NE) {  // NE%4==0 -> whole int4 valid
            int4 d4 = *(const int4*)(dst + idx);
            int4 s4 = *(const int4*)(src + idx);
            atomicAdd(&hD[d4.x >> 7], 1); atomicAdd(&hD[d4.y >> 7], 1);
            atomicAdd(&hD[d4.z >> 7], 1); atomicAdd(&hD[d4.w >> 7], 1);
            atomicAdd(&hS[s4.x >> 7], 1); atomicAdd(&hS[s4.y >> 7], 1);
            atomicAdd(&hS[s4.z >> 7], 1); atomicAdd(&hS[s4.w >> 7], 1);
        }
    }
    __syncthreads();
    for (int i = t; i < NBINS; i += 256) {
        int vD = hD[i]; cntD[(size_t)bb * NBINS + i] = vD; if (vD) atomicAdd(btD + i, vD);
        int vS = hS[i]; cntS[(size_t)bb * NBINS + i] = vS; if (vS) atomicAdd(btS + i, vS);
    }
}

// ---------------- scanA: exclusive scan of bin totals, 4 units ----------------
__global__ void k_scanA(const int* __restrict__ binTot, int* __restrict__ binBase,
                        int* __restrict__ off_su, int* __restrict__ off_sv) {
    __shared__ int s[NBINS];
    int u = blockIdx.x;  // 0=D_su 1=S_su 2=D_sv 3=S_sv
    const int* bt = binTot + u * NBINS;
    int* bb = binBase + u * (NBINS + 1);
    int t = threadIdx.x;
    for (int i = t; i < NBINS; i += 256) s[i] = bt[i];
    __syncthreads();
    if (t == 0) {
        int acc = 0;
        for (int i = 0; i < NBINS; i++) { int v = s[i]; s[i] = acc; acc += v; }
    }
    __syncthreads();
    for (int i = t; i < NBINS; i += 256) bb[i] = s[i];
    if (t == 0) bb[NBINS] = NE;
    if (t == 0 && u == 0) { off_su[NN] = NE; off_sv[NN] = NE; }
}

// ---------------- scanB: per-bin prefix over blocks, IN PLACE in cnt ----------------
__global__ void k_scanB(int* __restrict__ cnt4, const int* __restrict__ binBase) {
    __shared__ int s[NBLK];
    int u = blockIdx.x / NBINS, j = blockIdx.x % NBINS;
    int* cnt = cnt4 + (size_t)u * NBLK * NBINS;
    const int* bb = binBase + u * (NBINS + 1);
    int t = threadIdx.x;
    for (int i = t; i < NBLK; i += 256) s[i] = cnt[(size_t)i * NBINS + j];
    __syncthreads();
    if (t == 0) {
        int acc = bb[j];
        for (int i = 0; i < NBLK; i++) { int v = s[i]; s[i] = acc; acc += v; }
    }
    __syncthreads();
    for (int i = t; i < NBLK; i += 256) cnt[(size_t)i * NBINS + j] = s[i];
}

// ---------------- p3: dual scatter into bin order, BOTH graphs, packed payloads --------
// sortedD entry = src | (dst&127)<<20  (src<2^17; one int instead of int2: half traffic)
// sortedS entry = (uchar)(src&127)     (only the in-bin id is ever used: 1B instead of 4B)
__global__ __launch_bounds__(256) void k_p3(const int* __restrict__ srcA,
                                            const int* __restrict__ dstA,
                                            const int* __restrict__ srcB,
                                            const int* __restrict__ dstB,
                                            const int* __restrict__ cnt4,
                                            int* __restrict__ sdA, int* __restrict__ sdB,
                                            uchar_t* __restrict__ ssA,
                                            uchar_t* __restrict__ ssB) {
    __shared__ int curD[NBINS], curS[NBINS];
    int t = threadIdx.x, b = blockIdx.x;
    int g = (b >= NBLK) ? 1 : 0;
    int bb = b - g * NBLK;
    const int* src = g ? srcB : srcA;
    const int* dst = g ? dstB : dstA;
    const int* cntD = cnt4 + (size_t)(2 * g)     * NBLK * NBINS;
    const int* cntS = cnt4 + (size_t)(2 * g + 1) * NBLK * NBINS;
    int* sd = g ? sdB : sdA;
    uchar_t* ss = g ? ssB : ssA;
    for (int i = t; i < NBINS; i += 256) {
        curD[i] = cntD[(size_t)bb * NBINS + i];
        curS[i] = cntS[(size_t)bb * NBINS + i];
    }
    __syncthreads();
    int base = bb * EPB;
#pragma unroll
    for (int i = 0; i < EPB / 1024; i++) {
        int idx = base + i * 1024 + t * 4;
        if (idx < NE) {
            int4 s4 = *(const int4*)(src + idx);
            int4 d4 = *(const int4*)(dst + idx);
            int p;
            p = atomicAdd(&curD[d4.x >> 7], 1); sd[p] = s4.x | ((d4.x & 127) << 20);
            p = atomicAdd(&curD[d4.y >> 7], 1); sd[p] = s4.y | ((d4.y & 127) << 20);
            p = atomicAdd(&curD[d4.z >> 7], 1); sd[p] = s4.z | ((d4.z & 127) << 20);
            p = atomicAdd(&curD[d4.w >> 7], 1); sd[p] = s4.w | ((d4.w & 127) << 20);
            p = atomicAdd(&curS[s4.x >> 7], 1); ss[p] = (uchar_t)(s4.x & 127);
            p = atomicAdd(&curS[s4.y >> 7], 1); ss[p] = (uchar_t)(s4.y & 127);
            p = atomicAdd(&curS[s4.z >> 7], 1); ss[p] = (uchar_t)(s4.z & 127);
            p = atomicAdd(&curS[s4.w >> 7], 1); ss[p] = (uchar_t)(s4.w & 127);
        }
    }
}

// ---------------- p4: [0,2N) D counting-sort -> CSR per graph; [2N,4N) S hist ----------
__global__ __launch_bounds__(256) void k_p4(const int* __restrict__ sdA,
                                            const int* __restrict__ sdB,
                                            const uchar_t* __restrict__ ssA,
                                            const uchar_t* __restrict__ ssB,
                                            const int* __restrict__ binBase,
                                            int* __restrict__ offA, int* __restrict__ offB,
                                            int* __restrict__ edgesA,
                                            int* __restrict__ edgesB,
                                            int* __restrict__ csA, int* __restrict__ csB) {
    __shared__ int hist[BINW], pre[BINW], cur[BINW];
    int t = threadIdx.x;
    int u = blockIdx.x / NBINS, bin = blockIdx.x % NBINS;
    if (u < 2) {
        const int* sd = u ? sdB : sdA;
        const int* bb = binBase + (2 * u) * (NBINS + 1);
        int* off   = u ? offB : offA;
        int* edges = u ? edgesB : edgesA;
        if (t < BINW) hist[t] = 0;
        __syncthreads();
        int e0 = bb[bin], e1 = bb[bin + 1];
        for (int e = e0 + t; e < e1; e += 256)
            atomicAdd(&hist[sd[e] >> 20], 1);
        __syncthreads();
        if (t == 0) {
            int a = 0;
            for (int i = 0; i < BINW; i++) { pre[i] = a; a += hist[i]; }
        }
        __syncthreads();
        if (t < BINW) {
            cur[t] = pre[t];
            int node = bin * BINW + t;
            if (node < NN) off[node] = e0 + pre[t];
        }
        __syncthreads();
        for (int e = e0 + t; e < e1; e += 256) {
            int v = sd[e];
            int p = atomicAdd(&cur[v >> 20], 1);
            edges[e0 + p] = v & 0xFFFFF;
        }
    } else {
        const uchar_t* ss = (u == 3) ? ssB : ssA;
        const int* bb = binBase + (2 * (u - 2) + 1) * (NBINS + 1);
        int* cs = (u == 3) ? csB : csA;
        if (t < BINW) hist[t] = 0;
        __syncthreads();
        int e0 = bb[bin], e1 = bb[bin + 1];
        for (int e = e0 + t; e < e1; e += 256)
            atomicAdd(&hist[ss[e]], 1);
        __syncthreads();
        if (t < BINW) {
            int node = bin * BINW + t;
            if (node < NN) cs[node] = hist[t];
        }
    }
}

// ---------------- t1 (both graphs): y = (x*sn)@W1 (bf16) ----------------
__global__ __launch_bounds__(256) void k_t1(const float* __restrict__ xA,
                                            const float* __restrict__ xB,
                                            const float* __restrict__ W1,
                                            const int* __restrict__ csA,
                                            const int* __restrict__ csB,
                                            ushort_t* __restrict__ yA,
                                            ushort_t* __restrict__ yB) {
    __shared__ float sW[2048];
    __shared__ float sx[8 * 65];
    int g = blockIdx.y;
    const float* x = g ? xB : xA;
    const int* cnt_src = g ? csB : csA;
    ushort_t* y = g ? yB : yA;
    int t = threadIdx.x;
    int node0 = blockIdx.x * 8;
    for (int i = t; i < 2048; i += 256) sW[i] = W1[i];
    for (int i = t; i < 512; i += 256) {
        int r = i >> 6, k = i & 63;
        sx[r * 65 + k] = x[(size_t)(node0 + r) * 64 + k];
    }
    __syncthreads();
    int r = t >> 5, c = t & 31;
    int node = node0 + r;
    float sn = rsqrtf(fmaxf((float)cnt_src[node], 1.0f));
    float acc = 0.0f;
#pragma unroll
    for (int k = 0; k < 64; k++) acc += sx[r * 65 + k] * sW[k * 32 + c];
    acc *= sn;   // row scalar commutes with @W1
    y[(size_t)node * 32 + c] = (ushort_t)f2bf(acc);
}

// ---------------- t2 (both graphs): y2 = (HTb_rows(0..31)*sn)@W2 ----------------
__global__ __launch_bounds__(256) void k_t2(const ushort_t* __restrict__ HTbA,
                                            const ushort_t* __restrict__ HTbB,
                                            const float* __restrict__ W2,
                                            const int* __restrict__ csA,
                                            const int* __restrict__ csB,
                                            ushort_t* __restrict__ yA,
                                            ushort_t* __restrict__ yB) {
    __shared__ float sW[512];
    __shared__ float sx[16 * 33];
    int g = blockIdx.y;
    const ushort_t* HTb = g ? HTbB : HTbA;
    const int* cnt_src = g ? csB : csA;
    ushort_t* y2 = g ? yB : yA;
    int t = threadIdx.x;
    int node0 = blockIdx.x * 16;
    for (int i = t; i < 512; i += 256) sW[i] = W2[i];
    for (int i = t; i < 512; i += 256) {
        int r = i & 15, k = i >> 4;  // r fast -> coalesced over node dim
        sx[r * 33 + k] = bf2f(HTb[(size_t)k * NN + node0 + r]);
    }
    __syncthreads();
    int r = t >> 4, c = t & 15;
    int node = node0 + r;
    float sn = rsqrtf(fmaxf((float)cnt_src[node], 1.0f));
    float acc = 0.0f;
#pragma unroll
    for (int k = 0; k < 32; k++) acc += sx[r * 33 + k] * sW[k * 16 + c];
    acc *= sn;
    y2[(size_t)node * 16 + c] = (ushort_t)f2bf(acc);
}

// ---------------- CSR gather aggregation (both graphs), packed-uint y ----------------
template <int F, int RELU>
__global__ __launch_bounds__(256) void k_agg(
        const uint_t* __restrict__ yA, const uint_t* __restrict__ yB,
        const int* __restrict__ offA, const int* __restrict__ offB,
        const int* __restrict__ edgesA, const int* __restrict__ edgesB,
        const float* __restrict__ bias,
        ushort_t* __restrict__ HTbA, ushort_t* __restrict__ HTbB, int coloff) {
    constexpr int L = F / 2;
    constexpr int NPB = 256 / L;
    int gsel = blockIdx.y;
    const uint_t* y = gsel ? yB : yA;
    const int* off = gsel ? offB : offA;
    const int* edges = gsel ? edgesB : edgesA;
    ushort_t* HTb = gsel ? HTbB : HTbA;
    int t = threadIdx.x;
    int g = t / L, c2 = t % L;
    int node = blockIdx.x * NPB + g;
    int e0 = off[node], e1 = off[node + 1];
    int deg = e1 - e0;
    const int* srow = edges + e0;
    float a0 = 0.0f, a1 = 0.0f;
    int e = 0;
    for (; e + 3 < deg; e += 4) {
        int s0 = srow[e], s1 = srow[e + 1], s2 = srow[e + 2], s3 = srow[e + 3];
        uint_t u0 = y[(size_t)s0 * L + c2];
        uint_t u1 = y[(size_t)s1 * L + c2];
        uint_t u2 = y[(size_t)s2 * L + c2];
        uint_t u3 = y[(size_t)s3 * L + c2];
        a0 += __uint_as_float(u0 << 16) + __uint_as_float(u1 << 16)
            + __uint_as_float(u2 << 16) + __uint_as_float(u3 << 16);
        a1 += __uint_as_float(u0 & 0xFFFF0000u) + __uint_as_float(u1 & 0xFFFF0000u)
            + __uint_as_float(u2 & 0xFFFF0000u) + __uint_as_float(u3 & 0xFFFF0000u);
    }
    for (; e < deg; e++) {
        uint_t u = y[(size_t)srow[e] * L + c2];
        a0 += __uint_as_float(u << 16);
        a1 += __uint_as_float(u & 0xFFFF0000u);
    }
    float dn = rsqrtf(fmaxf((float)deg, 1.0f));
    float v0 = a0 * dn + bias[2 * c2];
    float v1 = a1 * dn + bias[2 * c2 + 1];
    if (RELU) { v0 = fmaxf(v0, 0.0f); v1 = fmaxf(v1, 0.0f); }
    HTb[(size_t)(coloff + 2 * c2) * NN + node] = (ushort_t)f2bf(v0);
    HTb[(size_t)(coloff + 2 * c2 + 1) * NN + node] = (ushort_t)f2bf(v1);
}

// one halfstep's 6 loads as STATICALLY-NAMED registers (rule #20 safe)
#define POOL_LOADS(J, KB)                                            \
    f32x4v a0_##J = *(const f32x4v*)(lrow + (KB));                   \
    f32x4v a1_##J = *(const f32x4v*)(lrow + (KB) + 4);               \
    short8v b0_##J = *(const short8v*)(hrow + (KB));                 \
    f32x4v a2_##J = *(const f32x4v*)(lrow + (KB) + 32);              \
    f32x4v a3_##J = *(const f32x4v*)(lrow + (KB) + 36);              \
    short8v b1_##J = *(const short8v*)(hrow + (KB) + 32);

#define POOL_MFMA2(J) do {                                                             \
    short8v av;                                                                        \
    av[0] = f2bf(a0_##J.x); av[1] = f2bf(a0_##J.y);                                    \
    av[2] = f2bf(a0_##J.z); av[3] = f2bf(a0_##J.w);                                    \
    av[4] = f2bf(a1_##J.x); av[5] = f2bf(a1_##J.y);                                    \
    av[6] = f2bf(a1_##J.z); av[7] = f2bf(a1_##J.w);                                    \
    acc = __builtin_amdgcn_mfma_f32_16x16x32_bf16(av, b0_##J, acc, 0, 0, 0);           \
    av[0] = f2bf(a2_##J.x); av[1] = f2bf(a2_##J.y);                                    \
    av[2] = f2bf(a2_##J.z); av[3] = f2bf(a2_##J.w);                                    \
    av[4] = f2bf(a3_##J.x); av[5] = f2bf(a3_##J.y);                                    \
    av[6] = f2bf(a3_##J.z); av[7] = f2bf(a3_##J.w);                                    \
    acc = __builtin_amdgcn_mfma_f32_16x16x32_bf16(av, b1_##J, acc, 0, 0, 0);           \
} while (0)

// ---------------- pooling v13: MFMA, grouped-4 explicit load window ----------------
// r19 diagnosis: compiler pins VGPR at 28 -> only ~6 loads in flight per wave; per-wave
// BW = 384B/~400cyc regardless of occupancy (2.1 TB/s plateau across r15-r19). Fix:
// hand-grouped loop -- 4 halfsteps' 24 loads issued as named live registers BEFORE any
// cvt/MFMA. Forces ~96 VGPR of load buffers (verify: VGPR_Count jumps to >100), 4x the
// per-wave load window. Remainder (<=3 halfsteps) + guarded tail keep the old body.
// Grid/config = r16-proven PNK16/PK6272 (PNK32 & XCD swizzle both regressed, r17/r18).
__global__ __launch_bounds__(384) void k_pool11(
        const float* __restrict__ lenA, const float* __restrict__ lenB,
        const ushort_t* __restrict__ HTbA, const ushort_t* __restrict__ HTbB,
        float* __restrict__ pooled) {
    __shared__ float red[3][64][4];
    const int mat = blockIdx.z;
    const float* __restrict__ len = mat ? lenB : lenA;
    const ushort_t* __restrict__ HTb = mat ? HTbB : HTbA;
    const int colbase = mat ? 48 : 0;
    const int b0 = blockIdx.x * 16;
    const int w = threadIdx.x >> 6;   // 0..5
    const int l = threadIdx.x & 63;
    const int c = w >> 1;             // col tile 0..2
    const int kh = w & 1;             // k-partner (even/odd 64-k blocks)
    const int rc = l & 15;
    const int seg = l >> 4;           // 0..3

    const int kc0 = blockIdx.y * PK;
    const int kend = (kc0 + PK < NN) ? (kc0 + PK) : NN;
    const float* lrow = len + (size_t)(b0 + rc) * NN;          // A row (graph b0+rc)
    const ushort_t* hrow = HTb + (size_t)(c * 16 + rc) * NN;   // B col (HTb row)

    f32x4v acc = {0.0f, 0.0f, 0.0f, 0.0f};

    const int kw0 = kc0 + kh * 64;            // this wave's first 64-k halfstep
    const int lb0 = kw0 + seg * 8;            // this lane's base
    int avail = kend - kw0;
    int T = (avail >= 64) ? ((avail - 64) >> 7) + 1 : 0;  // halfsteps fully in range

    int t = 0;
    for (; t + 4 <= T; t += 4) {
        int kb = lb0 + t * 128;
        POOL_LOADS(0, kb)
        POOL_LOADS(1, kb + 128)
        POOL_LOADS(2, kb + 256)
        POOL_LOADS(3, kb + 384)
        POOL_MFMA2(0);
        POOL_MFMA2(1);
        POOL_MFMA2(2);
        POOL_MFMA2(3);
    }
    for (; t < T; t++) {
        int kb = lb0 + t * 128;
        POOL_LOADS(r, kb)
        POOL_MFMA2(r);
    }

    // guarded tail halfstep (only the last k-chunk reaches here); 8|NN and 8|kend ->
    // a lane's 8-seg is valid iff kb < kend
    int kt = kw0 + T * 128;
    if (kt < kend) {
#pragma unroll
        for (int h = 0; h < 2; h++) {
            int kb = kt + h * 32 + seg * 8;
            short8v a = (short8v)0, b = (short8v)0;
            if (kb < kend) {
                f32x4v q0 = *(const f32x4v*)(lrow + kb);
                f32x4v q1 = *(const f32x4v*)(lrow + kb + 4);
                a[0] = f2bf(q0.x); a[1] = f2bf(q0.y); a[2] = f2bf(q0.z); a[3] = f2bf(q0.w);
                a[4] = f2bf(q1.x); a[5] = f2bf(q1.y); a[6] = f2bf(q1.z); a[7] = f2bf(q1.w);
                b = *(const short8v*)(hrow + kb);
            }
            acc = __builtin_amdgcn_mfma_f32_16x16x32_bf16(a, b, acc, 0, 0, 0);
        }
    }

    if (kh == 1) {
        *(f32x4v*)&red[c][l][0] = acc;
    }
    __syncthreads();
    if (kh == 0) {
        f32x4v o = *(const f32x4v*)&red[c][l][0];
#pragma unroll
        for (int r = 0; r < 4; r++) {
            float v = acc[r] + o[r];
            atomicAdd(&pooled[(b0 + seg * 4 + r) * 96 + colbase + c * 16 + rc], v);
        }
    }
}

// ---------------- MLP head ----------------
__global__ void k_mlp(const float* __restrict__ pooled,
                      const float* __restrict__ fc1w, const float* __restrict__ fc1b,
                      const float* __restrict__ fc2w, const float* __restrict__ fc2b,
                      const float* __restrict__ fc3w, const float* __restrict__ fc3b,
                      float* __restrict__ out) {
    __shared__ float srow[96];
    __shared__ float sh[64];
    __shared__ float sh2[16];
    int b = blockIdx.x, t = threadIdx.x; // 64 threads
    srow[t] = pooled[b * 96 + t];
    if (t < 32) srow[64 + t] = pooled[b * 96 + 64 + t];
    __syncthreads();
    float acc = fc1b[t];
    for (int k = 0; k < 96; k++) acc += srow[k] * fc1w[k * 64 + t];
    sh[t] = fmaxf(acc, 0.0f);
    __syncthreads();
    if (t < 16) {
        float a2 = fc2b[t];
        for (int k = 0; k < 64; k++) a2 += sh[k] * fc2w[k * 16 + t];
        sh2[t] = fmaxf(a2, 0.0f);
    }
    __syncthreads();
    if (t == 0) {
        float a3 = fc3b[0];
        for (int k = 0; k < 16; k++) a3 += sh2[k] * fc3w[k];
        out[b] = a3;
    }
}

extern "C" void kernel_launch(void* const* d_in, const int* in_sizes, int n_in,
                              void* d_out, int out_size, void* d_ws, size_t ws_size,
                              hipStream_t stream) {
    const float* solute_x  = (const float*)d_in[0];
    const float* solvent_x = (const float*)d_in[1];
    const float* su_len    = (const float*)d_in[2];
    const float* sv_len    = (const float*)d_in[3];
    const int*   su_src    = (const int*)d_in[4];
    const int*   su_dst    = (const int*)d_in[5];
    const int*   sv_src    = (const int*)d_in[6];
    const int*   sv_dst    = (const int*)d_in[7];
    const float* W1  = (const float*)d_in[8];
    const float* b1  = (const float*)d_in[9];
    const float* W2  = (const float*)d_in[10];
    const float* b2  = (const float*)d_in[11];
    const float* fc1w = (const float*)d_in[12];
    const float* fc1b = (const float*)d_in[13];
    const float* fc2w = (const float*)d_in[14];
    const float* fc2b = (const float*)d_in[15];
    const float* fc3w = (const float*)d_in[16];
    const float* fc3b = (const float*)d_in[17];
    float* out = (float*)d_out;

    // ---- arena (4B words), total ~64.4 MB ----
    char* ws = (char*)d_ws;
    size_t o = 0;
    auto alloc = [&](size_t elems) { void* p = ws + o * 4; o += elems; return p; };
    int* cnt4     = (int*)alloc((size_t)4 * NBLK * NBINS);  // [D_su][S_su][D_sv][S_sv]
    int* binTot   = (int*)alloc(4 * NBINS);
    int* binBase  = (int*)alloc(4 * (NBINS + 1));
    int* off_su   = (int*)alloc(NN + 1);
    int* off_sv   = (int*)alloc(NN + 1);
    int* csrc_su  = (int*)alloc(NN);
    int* csrc_sv  = (int*)alloc(NN);
    float* pooled = (float*)alloc(NB * 96);
    int* edges_su = (int*)alloc(NE);
    int* edges_sv = (int*)alloc(NE);
    o = (o + 1) & ~(size_t)1;                 // 8B align
    // union region X (32 MB):
    //   build:   sdA int NE (12.8) | sdB int NE (12.8) | ssA uchar NE (3.2) | ssB (3.2)
    //   compute: ybuf_su 6.4 | ybuf_sv 6.4 | HTb_su 9.6 | HTb_sv 9.6
    char* X = ws + o * 4;
    int*      sdA     = (int*)X;
    int*      sdB     = (int*)(X + (size_t)NE * 4);
    uchar_t*  ssA     = (uchar_t*)(X + (size_t)NE * 8);
    uchar_t*  ssB     = (uchar_t*)(X + (size_t)NE * 9);
    uint_t*   ybuf_su = (uint_t*)X;
    uint_t*   ybuf_sv = (uint_t*)(X + (size_t)NN * 64);
    ushort_t* HTb_su  = (ushort_t*)(X + (size_t)NN * 128);
    ushort_t* HTb_sv  = (ushort_t*)(X + (size_t)NN * 128 + (size_t)NN * 96);

    hipMemsetAsync(binTot, 0, 4 * NBINS * 4, stream);
    hipMemsetAsync(pooled, 0, NB * 96 * 4, stream);

    // ==== phase 1: sort-based CSR build, both graphs, merged launches ====
    k_p1<<<2 * NBLK, 256, 0, stream>>>(su_src, su_dst, sv_src, sv_dst, cnt4, binTot);
    k_scanA<<<4, 256, 0, stream>>>(binTot, binBase, off_su, off_sv);
    k_scanB<<<4 * NBINS, 256, 0, stream>>>(cnt4, binBase);
    k_p3<<<2 * NBLK, 256, 0, stream>>>(su_src, su_dst, sv_src, sv_dst, cnt4,
                                       sdA, sdB, ssA, ssB);
    k_p4<<<4 * NBINS, 256, 0, stream>>>(sdA, sdB, ssA, ssB, binBase,
                                        off_su, off_sv, edges_su, edges_sv,
                                        csrc_su, csrc_sv);

    // ==== phase 2: GCN layers, both graphs per launch (sorted buffers now dead) ====
    {
        dim3 g1(NN / 8, 2);
        k_t1<<<g1, 256, 0, stream>>>(solute_x, solvent_x, W1, csrc_su, csrc_sv,
                                     (ushort_t*)ybuf_su, (ushort_t*)ybuf_sv);
        dim3 g2(NN / 16, 2);
        k_agg<32, 1><<<g2, 256, 0, stream>>>(ybuf_su, ybuf_sv, off_su, off_sv,
                                             edges_su, edges_sv, b1, HTb_su, HTb_sv, 0);
        k_t2<<<g2, 256, 0, stream>>>(HTb_su, HTb_sv, W2, csrc_su, csrc_sv,
                                     (ushort_t*)ybuf_su, (ushort_t*)ybuf_sv);
        dim3 g3(NN / 32, 2);
        k_agg<16, 0><<<g3, 256, 0, stream>>>(ybuf_su, ybuf_sv, off_su, off_sv,
                                             edges_su, edges_sv, b2, HTb_su, HTb_sv, 32);
    }

    // ==== pooling (MFMA, grouped loads) + MLP ====
    {
        dim3 gr(NB / 16, PNK, 2);
        k_pool11<<<gr, 384, 0, stream>>>(su_len, sv_len, HTb_su, HTb_sv, pooled);
    }
    k_mlp<<<NB, 64, 0, stream>>>(pooled, fc1w, fc1b, fc2w, fc2b, fc3w, fc3b, out);
}

// Round 21
// 647.006 us; speedup vs baseline: 1.2173x; 1.2173x over previous
//
#include <hip/hip_runtime.h>
#include <hip/hip_bf16.h>

#define NN 100000
#define NE 3200000
#define NB 512
#define BINW 128                  // nodes per bin (bin = node >> 7)
#define NBINS 782                 // ceil(NN / 128); 782*128 = 100096
#define EPB 8192                  // edges per p1/p3 block
#define NBLK 391                  // ceil(NE / EPB)
#define PK 6400                   // pool k-chunk (25*256; 16*6400 = 102400 >= NN)
#define PNK 16

typedef unsigned short ushort_t;
typedef unsigned int uint_t;
typedef unsigned char uchar_t;
typedef __attribute__((ext_vector_type(8))) short short8v;   // 8 bf16 (4 VGPRs)
typedef __attribute__((ext_vector_type(4))) float f32x4v;

static __device__ __forceinline__ short f2bf(float f) {
    __hip_bfloat16 h = __float2bfloat16(f);
    return *reinterpret_cast<short*>(&h);
}
static __device__ __forceinline__ float bf2f(ushort_t u) {
    return __uint_as_float(((uint_t)u) << 16);
}

// ---------------- p1: per-block bin-histograms (dst AND src), BOTH graphs ----------------
__global__ __launch_bounds__(256) void k_p1(const int* __restrict__ srcA,
                                            const int* __restrict__ dstA,
                                            const int* __restrict__ srcB,
                                            const int* __restrict__ dstB,
                                            int* __restrict__ cnt4,
                                            int* __restrict__ binTot) {
    __shared__ int hD[NBINS], hS[NBINS];
    int t = threadIdx.x, b = blockIdx.x;
    int g = (b >= NBLK) ? 1 : 0;
    int bb = b - g * NBLK;
    const int* src = g ? srcB : srcA;
    const int* dst = g ? dstB : dstA;
    int* cntD = cnt4 + (size_t)(2 * g)     * NBLK * NBINS;
    int* cntS = cnt4 + (size_t)(2 * g + 1) * NBLK * NBINS;
    int* btD  = binTot + (2 * g) * NBINS;
    int* btS  = binTot + (2 * g + 1) * NBINS;
    for (int i = t; i < NBINS; i += 256) { hD[i] = 0; hS[i] = 0; }
    __syncthreads();
    int base = bb * EPB;
#pragma unroll
    for (int i = 0; i < EPB / 1024; i++) {
        int idx = base + i * 1024 + t * 4;
        if (idx < NE) {  // NE%4==0 -> whole int4 valid
            int4 d4 = *(const int4*)(dst + idx);
            int4 s4 = *(const int4*)(src + idx);
            atomicAdd(&hD[d4.x >> 7], 1); atomicAdd(&hD[d4.y >> 7], 1);
            atomicAdd(&hD[d4.z >> 7], 1); atomicAdd(&hD[d4.w >> 7], 1);
            atomicAdd(&hS[s4.x >> 7], 1); atomicAdd(&hS[s4.y >> 7], 1);
            atomicAdd(&hS[s4.z >> 7], 1); atomicAdd(&hS[s4.w >> 7], 1);
        }
    }
    __syncthreads();
    for (int i = t; i < NBINS; i += 256) {
        int vD = hD[i]; cntD[(size_t)bb * NBINS + i] = vD; if (vD) atomicAdd(btD + i, vD);
        int vS = hS[i]; cntS[(size_t)bb * NBINS + i] = vS; if (vS) atomicAdd(btS + i, vS);
    }
}

// ---------------- scanA: exclusive scan of bin totals, 4 units ----------------
__global__ void k_scanA(const int* __restrict__ binTot, int* __restrict__ binBase,
                        int* __restrict__ off_su, int* __restrict__ off_sv) {
    __shared__ int s[NBINS];
    int u = blockIdx.x;  // 0=D_su 1=S_su 2=D_sv 3=S_sv
    const int* bt = binTot + u * NBINS;
    int* bb = binBase + u * (NBINS + 1);
    int t = threadIdx.x;
    for (int i = t; i < NBINS; i += 256) s[i] = bt[i];
    __syncthreads();
    if (t == 0) {
        int acc = 0;
        for (int i = 0; i < NBINS; i++) { int v = s[i]; s[i] = acc; acc += v; }
    }
    __syncthreads();
    for (int i = t; i < NBINS; i += 256) bb[i] = s[i];
    if (t == 0) bb[NBINS] = NE;
    if (t == 0 && u == 0) { off_su[NN] = NE; off_sv[NN] = NE; }
}

// ---------------- scanB: per-bin prefix over blocks, IN PLACE in cnt ----------------
__global__ void k_scanB(int* __restrict__ cnt4, const int* __restrict__ binBase) {
    __shared__ int s[NBLK];
    int u = blockIdx.x / NBINS, j = blockIdx.x % NBINS;
    int* cnt = cnt4 + (size_t)u * NBLK * NBINS;
    const int* bb = binBase + u * (NBINS + 1);
    int t = threadIdx.x;
    for (int i = t; i < NBLK; i += 256) s[i] = cnt[(size_t)i * NBINS + j];
    __syncthreads();
    if (t == 0) {
        int acc = bb[j];
        for (int i = 0; i < NBLK; i++) { int v = s[i]; s[i] = acc; acc += v; }
    }
    __syncthreads();
    for (int i = t; i < NBLK; i += 256) cnt[(size_t)i * NBINS + j] = s[i];
}

// ---------------- p3: dual scatter into bin order, BOTH graphs, packed payloads --------
// sortedD entry = src | (dst&127)<<20  (src<2^17; one int instead of int2: half traffic)
// sortedS entry = (uchar)(src&127)     (only the in-bin id is ever used: 1B instead of 4B)
__global__ __launch_bounds__(256) void k_p3(const int* __restrict__ srcA,
                                            const int* __restrict__ dstA,
                                            const int* __restrict__ srcB,
                                            const int* __restrict__ dstB,
                                            const int* __restrict__ cnt4,
                                            int* __restrict__ sdA, int* __restrict__ sdB,
                                            uchar_t* __restrict__ ssA,
                                            uchar_t* __restrict__ ssB) {
    __shared__ int curD[NBINS], curS[NBINS];
    int t = threadIdx.x, b = blockIdx.x;
    int g = (b >= NBLK) ? 1 : 0;
    int bb = b - g * NBLK;
    const int* src = g ? srcB : srcA;
    const int* dst = g ? dstB : dstA;
    const int* cntD = cnt4 + (size_t)(2 * g)     * NBLK * NBINS;
    const int* cntS = cnt4 + (size_t)(2 * g + 1) * NBLK * NBINS;
    int* sd = g ? sdB : sdA;
    uchar_t* ss = g ? ssB : ssA;
    for (int i = t; i < NBINS; i += 256) {
        curD[i] = cntD[(size_t)bb * NBINS + i];
        curS[i] = cntS[(size_t)bb * NBINS + i];
    }
    __syncthreads();
    int base = bb * EPB;
#pragma unroll
    for (int i = 0; i < EPB / 1024; i++) {
        int idx = base + i * 1024 + t * 4;
        if (idx < NE) {
            int4 s4 = *(const int4*)(src + idx);
            int4 d4 = *(const int4*)(dst + idx);
            int p;
            p = atomicAdd(&curD[d4.x >> 7], 1); sd[p] = s4.x | ((d4.x & 127) << 20);
            p = atomicAdd(&curD[d4.y >> 7], 1); sd[p] = s4.y | ((d4.y & 127) << 20);
            p = atomicAdd(&curD[d4.z >> 7], 1); sd[p] = s4.z | ((d4.z & 127) << 20);
            p = atomicAdd(&curD[d4.w >> 7], 1); sd[p] = s4.w | ((d4.w & 127) << 20);
            p = atomicAdd(&curS[s4.x >> 7], 1); ss[p] = (uchar_t)(s4.x & 127);
            p = atomicAdd(&curS[s4.y >> 7], 1); ss[p] = (uchar_t)(s4.y & 127);
            p = atomicAdd(&curS[s4.z >> 7], 1); ss[p] = (uchar_t)(s4.z & 127);
            p = atomicAdd(&curS[s4.w >> 7], 1); ss[p] = (uchar_t)(s4.w & 127);
        }
    }
}

// ---------------- p4: [0,2N) D counting-sort -> CSR per graph; [2N,4N) S hist ----------
__global__ __launch_bounds__(256) void k_p4(const int* __restrict__ sdA,
                                            const int* __restrict__ sdB,
                                            const uchar_t* __restrict__ ssA,
                                            const uchar_t* __restrict__ ssB,
                                            const int* __restrict__ binBase,
                                            int* __restrict__ offA, int* __restrict__ offB,
                                            int* __restrict__ edgesA,
                                            int* __restrict__ edgesB,
                                            int* __restrict__ csA, int* __restrict__ csB) {
    __shared__ int hist[BINW], pre[BINW], cur[BINW];
    int t = threadIdx.x;
    int u = blockIdx.x / NBINS, bin = blockIdx.x % NBINS;
    if (u < 2) {
        const int* sd = u ? sdB : sdA;
        const int* bb = binBase + (2 * u) * (NBINS + 1);
        int* off   = u ? offB : offA;
        int* edges = u ? edgesB : edgesA;
        if (t < BINW) hist[t] = 0;
        __syncthreads();
        int e0 = bb[bin], e1 = bb[bin + 1];
        for (int e = e0 + t; e < e1; e += 256)
            atomicAdd(&hist[sd[e] >> 20], 1);
        __syncthreads();
        if (t == 0) {
            int a = 0;
            for (int i = 0; i < BINW; i++) { pre[i] = a; a += hist[i]; }
        }
        __syncthreads();
        if (t < BINW) {
            cur[t] = pre[t];
            int node = bin * BINW + t;
            if (node < NN) off[node] = e0 + pre[t];
        }
        __syncthreads();
        for (int e = e0 + t; e < e1; e += 256) {
            int v = sd[e];
            int p = atomicAdd(&cur[v >> 20], 1);
            edges[e0 + p] = v & 0xFFFFF;
        }
    } else {
        const uchar_t* ss = (u == 3) ? ssB : ssA;
        const int* bb = binBase + (2 * (u - 2) + 1) * (NBINS + 1);
        int* cs = (u == 3) ? csB : csA;
        if (t < BINW) hist[t] = 0;
        __syncthreads();
        int e0 = bb[bin], e1 = bb[bin + 1];
        for (int e = e0 + t; e < e1; e += 256)
            atomicAdd(&hist[ss[e]], 1);
        __syncthreads();
        if (t < BINW) {
            int node = bin * BINW + t;
            if (node < NN) cs[node] = hist[t];
        }
    }
}

// ---------------- t1 (both graphs): y = (x*sn)@W1 (bf16) ----------------
__global__ __launch_bounds__(256) void k_t1(const float* __restrict__ xA,
                                            const float* __restrict__ xB,
                                            const float* __restrict__ W1,
                                            const int* __restrict__ csA,
                                            const int* __restrict__ csB,
                                            ushort_t* __restrict__ yA,
                                            ushort_t* __restrict__ yB) {
    __shared__ float sW[2048];
    __shared__ float sx[8 * 65];
    int g = blockIdx.y;
    const float* x = g ? xB : xA;
    const int* cnt_src = g ? csB : csA;
    ushort_t* y = g ? yB : yA;
    int t = threadIdx.x;
    int node0 = blockIdx.x * 8;
    for (int i = t; i < 2048; i += 256) sW[i] = W1[i];
    for (int i = t; i < 512; i += 256) {
        int r = i >> 6, k = i & 63;
        sx[r * 65 + k] = x[(size_t)(node0 + r) * 64 + k];
    }
    __syncthreads();
    int r = t >> 5, c = t & 31;
    int node = node0 + r;
    float sn = rsqrtf(fmaxf((float)cnt_src[node], 1.0f));
    float acc = 0.0f;
#pragma unroll
    for (int k = 0; k < 64; k++) acc += sx[r * 65 + k] * sW[k * 32 + c];
    acc *= sn;   // row scalar commutes with @W1
    y[(size_t)node * 32 + c] = (ushort_t)f2bf(acc);
}

// ---------------- t2 (both graphs): y2 = (HTb_rows(0..31)*sn)@W2 ----------------
__global__ __launch_bounds__(256) void k_t2(const ushort_t* __restrict__ HTbA,
                                            const ushort_t* __restrict__ HTbB,
                                            const float* __restrict__ W2,
                                            const int* __restrict__ csA,
                                            const int* __restrict__ csB,
                                            ushort_t* __restrict__ yA,
                                            ushort_t* __restrict__ yB) {
    __shared__ float sW[512];
    __shared__ float sx[16 * 33];
    int g = blockIdx.y;
    const ushort_t* HTb = g ? HTbB : HTbA;
    const int* cnt_src = g ? csB : csA;
    ushort_t* y2 = g ? yB : yA;
    int t = threadIdx.x;
    int node0 = blockIdx.x * 16;
    for (int i = t; i < 512; i += 256) sW[i] = W2[i];
    for (int i = t; i < 512; i += 256) {
        int r = i & 15, k = i >> 4;  // r fast -> coalesced over node dim
        sx[r * 33 + k] = bf2f(HTb[(size_t)k * NN + node0 + r]);
    }
    __syncthreads();
    int r = t >> 4, c = t & 15;
    int node = node0 + r;
    float sn = rsqrtf(fmaxf((float)cnt_src[node], 1.0f));
    float acc = 0.0f;
#pragma unroll
    for (int k = 0; k < 32; k++) acc += sx[r * 33 + k] * sW[k * 16 + c];
    acc *= sn;
    y2[(size_t)node * 16 + c] = (ushort_t)f2bf(acc);
}

// ---------------- CSR gather aggregation (both graphs), packed-uint y ----------------
template <int F, int RELU>
__global__ __launch_bounds__(256) void k_agg(
        const uint_t* __restrict__ yA, const uint_t* __restrict__ yB,
        const int* __restrict__ offA, const int* __restrict__ offB,
        const int* __restrict__ edgesA, const int* __restrict__ edgesB,
        const float* __restrict__ bias,
        ushort_t* __restrict__ HTbA, ushort_t* __restrict__ HTbB, int coloff) {
    constexpr int L = F / 2;
    constexpr int NPB = 256 / L;
    int gsel = blockIdx.y;
    const uint_t* y = gsel ? yB : yA;
    const int* off = gsel ? offB : offA;
    const int* edges = gsel ? edgesB : edgesA;
    ushort_t* HTb = gsel ? HTbB : HTbA;
    int t = threadIdx.x;
    int g = t / L, c2 = t % L;
    int node = blockIdx.x * NPB + g;
    int e0 = off[node], e1 = off[node + 1];
    int deg = e1 - e0;
    const int* srow = edges + e0;
    float a0 = 0.0f, a1 = 0.0f;
    int e = 0;
    for (; e + 3 < deg; e += 4) {
        int s0 = srow[e], s1 = srow[e + 1], s2 = srow[e + 2], s3 = srow[e + 3];
        uint_t u0 = y[(size_t)s0 * L + c2];
        uint_t u1 = y[(size_t)s1 * L + c2];
        uint_t u2 = y[(size_t)s2 * L + c2];
        uint_t u3 = y[(size_t)s3 * L + c2];
        a0 += __uint_as_float(u0 << 16) + __uint_as_float(u1 << 16)
            + __uint_as_float(u2 << 16) + __uint_as_float(u3 << 16);
        a1 += __uint_as_float(u0 & 0xFFFF0000u) + __uint_as_float(u1 & 0xFFFF0000u)
            + __uint_as_float(u2 & 0xFFFF0000u) + __uint_as_float(u3 & 0xFFFF0000u);
    }
    for (; e < deg; e++) {
        uint_t u = y[(size_t)srow[e] * L + c2];
        a0 += __uint_as_float(u << 16);
        a1 += __uint_as_float(u & 0xFFFF0000u);
    }
    float dn = rsqrtf(fmaxf((float)deg, 1.0f));
    float v0 = a0 * dn + bias[2 * c2];
    float v1 = a1 * dn + bias[2 * c2 + 1];
    if (RELU) { v0 = fmaxf(v0, 0.0f); v1 = fmaxf(v1, 0.0f); }
    HTb[(size_t)(coloff + 2 * c2) * NN + node] = (ushort_t)f2bf(v0);
    HTb[(size_t)(coloff + 2 * c2 + 1) * NN + node] = (ushort_t)f2bf(v1);
}

// ---------------- pooling v14: MFMA, A-amortized wave tile (16g x 48c per wave) --------
// r15-r20 evidence: pool pinned at ~2.1TB/s, VALUBusy 4%, MfmaUtil 1.8% across all load/
// occupancy configs -> bottleneck is vmem-instruction rate, and the 3 col-waves of the old
// block redundantly loaded the SAME len rows (3x A traffic). New tile: block = 4 waves =
// 4 k-partners; each wave computes ALL 48 cols: A loaded once (4 loads + 1 cvt pass),
// reused for 6 MFMAs with 6 B loads -> 10 vmem / 6 MFMA vs 18 / 6 before. No LDS/barriers
// in main loop; one end-of-kernel 4-way reduce. k-stride per wave = 256.
// Frag layouts (guide §3, m89-verified): A lane l -> row l&15, k=(l>>4)*8+i; B lane l ->
// col l&15, same k; C/D lane l reg r -> row (l>>4)*4+r, col l&15.
__global__ __launch_bounds__(256) void k_pool12(
        const float* __restrict__ lenA, const float* __restrict__ lenB,
        const ushort_t* __restrict__ HTbA, const ushort_t* __restrict__ HTbB,
        float* __restrict__ pooled) {
    __shared__ float red[3][3][64][4];   // [wave-1][ctile][lane][reg]
    const int mat = blockIdx.z;
    const float* __restrict__ len = mat ? lenB : lenA;
    const ushort_t* __restrict__ HTb = mat ? HTbB : HTbA;
    const int colbase = mat ? 48 : 0;
    const int b0 = blockIdx.x * 16;
    const int w = threadIdx.x >> 6;   // k-partner 0..3
    const int l = threadIdx.x & 63;
    const int rc = l & 15;
    const int seg = l >> 4;           // 0..3

    const int kc0 = blockIdx.y * PK;
    const int kend = (kc0 + PK < NN) ? (kc0 + PK) : NN;
    const float* lrow = len + (size_t)(b0 + rc) * NN;
    const ushort_t* h0 = HTb + (size_t)(0 * 16 + rc) * NN;
    const ushort_t* h1 = HTb + (size_t)(1 * 16 + rc) * NN;
    const ushort_t* h2 = HTb + (size_t)(2 * 16 + rc) * NN;

    f32x4v acc0 = {0, 0, 0, 0}, acc1 = {0, 0, 0, 0}, acc2 = {0, 0, 0, 0};

    const int kw0 = kc0 + w * 64;     // this wave's first halfstep base (stride 256)
    const int lb0 = kw0 + seg * 8;
    int avail = kend - kw0;
    int T = (avail >= 64) ? ((avail - 64) >> 8) + 1 : 0;  // full 64-k halfsteps

    for (int t = 0; t < T; t++) {
        int kb = lb0 + t * 256;
        // A: load once, convert once
        f32x4v q0 = *(const f32x4v*)(lrow + kb);
        f32x4v q1 = *(const f32x4v*)(lrow + kb + 4);
        f32x4v q2 = *(const f32x4v*)(lrow + kb + 32);
        f32x4v q3 = *(const f32x4v*)(lrow + kb + 36);
        // B: 6 loads (3 col tiles x 2 k-halves)
        short8v b00 = *(const short8v*)(h0 + kb);
        short8v b01 = *(const short8v*)(h0 + kb + 32);
        short8v b10 = *(const short8v*)(h1 + kb);
        short8v b11 = *(const short8v*)(h1 + kb + 32);
        short8v b20 = *(const short8v*)(h2 + kb);
        short8v b21 = *(const short8v*)(h2 + kb + 32);
        short8v A0, A1;
        A0[0] = f2bf(q0.x); A0[1] = f2bf(q0.y); A0[2] = f2bf(q0.z); A0[3] = f2bf(q0.w);
        A0[4] = f2bf(q1.x); A0[5] = f2bf(q1.y); A0[6] = f2bf(q1.z); A0[7] = f2bf(q1.w);
        A1[0] = f2bf(q2.x); A1[1] = f2bf(q2.y); A1[2] = f2bf(q2.z); A1[3] = f2bf(q2.w);
        A1[4] = f2bf(q3.x); A1[5] = f2bf(q3.y); A1[6] = f2bf(q3.z); A1[7] = f2bf(q3.w);
        acc0 = __builtin_amdgcn_mfma_f32_16x16x32_bf16(A0, b00, acc0, 0, 0, 0);
        acc0 = __builtin_amdgcn_mfma_f32_16x16x32_bf16(A1, b01, acc0, 0, 0, 0);
        acc1 = __builtin_amdgcn_mfma_f32_16x16x32_bf16(A0, b10, acc1, 0, 0, 0);
        acc1 = __builtin_amdgcn_mfma_f32_16x16x32_bf16(A1, b11, acc1, 0, 0, 0);
        acc2 = __builtin_amdgcn_mfma_f32_16x16x32_bf16(A0, b20, acc2, 0, 0, 0);
        acc2 = __builtin_amdgcn_mfma_f32_16x16x32_bf16(A1, b21, acc2, 0, 0, 0);
    }

    // guarded tail halfstep (remaining < 64 k); 8|NN and 8|kend -> seg valid iff kb<kend
    int kt = kw0 + T * 256;
    if (kt < kend) {
#pragma unroll
        for (int h = 0; h < 2; h++) {
            int kb = kt + h * 32 + seg * 8;
            short8v a = (short8v)0, v0 = (short8v)0, v1 = (short8v)0, v2 = (short8v)0;
            if (kb < kend) {
                f32x4v q0 = *(const f32x4v*)(lrow + kb);
                f32x4v q1 = *(const f32x4v*)(lrow + kb + 4);
                a[0] = f2bf(q0.x); a[1] = f2bf(q0.y); a[2] = f2bf(q0.z); a[3] = f2bf(q0.w);
                a[4] = f2bf(q1.x); a[5] = f2bf(q1.y); a[6] = f2bf(q1.z); a[7] = f2bf(q1.w);
                v0 = *(const short8v*)(h0 + kb);
                v1 = *(const short8v*)(h1 + kb);
                v2 = *(const short8v*)(h2 + kb);
            }
            acc0 = __builtin_amdgcn_mfma_f32_16x16x32_bf16(a, v0, acc0, 0, 0, 0);
            acc1 = __builtin_amdgcn_mfma_f32_16x16x32_bf16(a, v1, acc1, 0, 0, 0);
            acc2 = __builtin_amdgcn_mfma_f32_16x16x32_bf16(a, v2, acc2, 0, 0, 0);
        }
    }

    // 4-way k-partner reduce via LDS; wave 0 finishes with atomics
    if (w > 0) {
        *(f32x4v*)&red[w - 1][0][l][0] = acc0;
        *(f32x4v*)&red[w - 1][1][l][0] = acc1;
        *(f32x4v*)&red[w - 1][2][l][0] = acc2;
    }
    __syncthreads();
    if (w == 0) {
        f32x4v s0 = acc0, s1 = acc1, s2 = acc2;
#pragma unroll
        for (int j = 0; j < 3; j++) {
            s0 += *(const f32x4v*)&red[j][0][l][0];
            s1 += *(const f32x4v*)&red[j][1][l][0];
            s2 += *(const f32x4v*)&red[j][2][l][0];
        }
#pragma unroll
        for (int r = 0; r < 4; r++) {
            int row = (b0 + seg * 4 + r) * 96 + colbase;
            atomicAdd(&pooled[row + 0 * 16 + rc], s0[r]);
            atomicAdd(&pooled[row + 1 * 16 + rc], s1[r]);
            atomicAdd(&pooled[row + 2 * 16 + rc], s2[r]);
        }
    }
}

// ---------------- MLP head ----------------
__global__ void k_mlp(const float* __restrict__ pooled,
                      const float* __restrict__ fc1w, const float* __restrict__ fc1b,
                      const float* __restrict__ fc2w, const float* __restrict__ fc2b,
                      const float* __restrict__ fc3w, const float* __restrict__ fc3b,
                      float* __restrict__ out) {
    __shared__ float srow[96];
    __shared__ float sh[64];
    __shared__ float sh2[16];
    int b = blockIdx.x, t = threadIdx.x; // 64 threads
    srow[t] = pooled[b * 96 + t];
    if (t < 32) srow[64 + t] = pooled[b * 96 + 64 + t];
    __syncthreads();
    float acc = fc1b[t];
    for (int k = 0; k < 96; k++) acc += srow[k] * fc1w[k * 64 + t];
    sh[t] = fmaxf(acc, 0.0f);
    __syncthreads();
    if (t < 16) {
        float a2 = fc2b[t];
        for (int k = 0; k < 64; k++) a2 += sh[k] * fc2w[k * 16 + t];
        sh2[t] = fmaxf(a2, 0.0f);
    }
    __syncthreads();
    if (t == 0) {
        float a3 = fc3b[0];
        for (int k = 0; k < 16; k++) a3 += sh2[k] * fc3w[k];
        out[b] = a3;
    }
}

extern "C" void kernel_launch(void* const* d_in, const int* in_sizes, int n_in,
                              void* d_out, int out_size, void* d_ws, size_t ws_size,
                              hipStream_t stream) {
    const float* solute_x  = (const float*)d_in[0];
    const float* solvent_x = (const float*)d_in[1];
    const float* su_len    = (const float*)d_in[2];
    const float* sv_len    = (const float*)d_in[3];
    const int*   su_src    = (const int*)d_in[4];
    const int*   su_dst    = (const int*)d_in[5];
    const int*   sv_src    = (const int*)d_in[6];
    const int*   sv_dst    = (const int*)d_in[7];
    const float* W1  = (const float*)d_in[8];
    const float* b1  = (const float*)d_in[9];
    const float* W2  = (const float*)d_in[10];
    const float* b2  = (const float*)d_in[11];
    const float* fc1w = (const float*)d_in[12];
    const float* fc1b = (const float*)d_in[13];
    const float* fc2w = (const float*)d_in[14];
    const float* fc2b = (const float*)d_in[15];
    const float* fc3w = (const float*)d_in[16];
    const float* fc3b = (const float*)d_in[17];
    float* out = (float*)d_out;

    // ---- arena (4B words), total ~64.4 MB ----
    char* ws = (char*)d_ws;
    size_t o = 0;
    auto alloc = [&](size_t elems) { void* p = ws + o * 4; o += elems; return p; };
    int* cnt4     = (int*)alloc((size_t)4 * NBLK * NBINS);  // [D_su][S_su][D_sv][S_sv]
    int* binTot   = (int*)alloc(4 * NBINS);
    int* binBase  = (int*)alloc(4 * (NBINS + 1));
    int* off_su   = (int*)alloc(NN + 1);
    int* off_sv   = (int*)alloc(NN + 1);
    int* csrc_su  = (int*)alloc(NN);
    int* csrc_sv  = (int*)alloc(NN);
    float* pooled = (float*)alloc(NB * 96);
    int* edges_su = (int*)alloc(NE);
    int* edges_sv = (int*)alloc(NE);
    o = (o + 1) & ~(size_t)1;                 // 8B align
    // union region X (32 MB):
    //   build:   sdA int NE (12.8) | sdB int NE (12.8) | ssA uchar NE (3.2) | ssB (3.2)
    //   compute: ybuf_su 6.4 | ybuf_sv 6.4 | HTb_su 9.6 | HTb_sv 9.6
    char* X = ws + o * 4;
    int*      sdA     = (int*)X;
    int*      sdB     = (int*)(X + (size_t)NE * 4);
    uchar_t*  ssA     = (uchar_t*)(X + (size_t)NE * 8);
    uchar_t*  ssB     = (uchar_t*)(X + (size_t)NE * 9);
    uint_t*   ybuf_su = (uint_t*)X;
    uint_t*   ybuf_sv = (uint_t*)(X + (size_t)NN * 64);
    ushort_t* HTb_su  = (ushort_t*)(X + (size_t)NN * 128);
    ushort_t* HTb_sv  = (ushort_t*)(X + (size_t)NN * 128 + (size_t)NN * 96);

    hipMemsetAsync(binTot, 0, 4 * NBINS * 4, stream);
    hipMemsetAsync(pooled, 0, NB * 96 * 4, stream);

    // ==== phase 1: sort-based CSR build, both graphs, merged launches ====
    k_p1<<<2 * NBLK, 256, 0, stream>>>(su_src, su_dst, sv_src, sv_dst, cnt4, binTot);
    k_scanA<<<4, 256, 0, stream>>>(binTot, binBase, off_su, off_sv);
    k_scanB<<<4 * NBINS, 256, 0, stream>>>(cnt4, binBase);
    k_p3<<<2 * NBLK, 256, 0, stream>>>(su_src, su_dst, sv_src, sv_dst, cnt4,
                                       sdA, sdB, ssA, ssB);
    k_p4<<<4 * NBINS, 256, 0, stream>>>(sdA, sdB, ssA, ssB, binBase,
                                        off_su, off_sv, edges_su, edges_sv,
                                        csrc_su, csrc_sv);

    // ==== phase 2: GCN layers, both graphs per launch (sorted buffers now dead) ====
    {
        dim3 g1(NN / 8, 2);
        k_t1<<<g1, 256, 0, stream>>>(solute_x, solvent_x, W1, csrc_su, csrc_sv,
                                     (ushort_t*)ybuf_su, (ushort_t*)ybuf_sv);
        dim3 g2(NN / 16, 2);
        k_agg<32, 1><<<g2, 256, 0, stream>>>(ybuf_su, ybuf_sv, off_su, off_sv,
                                             edges_su, edges_sv, b1, HTb_su, HTb_sv, 0);
        k_t2<<<g2, 256, 0, stream>>>(HTb_su, HTb_sv, W2, csrc_su, csrc_sv,
                                     (ushort_t*)ybuf_su, (ushort_t*)ybuf_sv);
        dim3 g3(NN / 32, 2);
        k_agg<16, 0><<<g3, 256, 0, stream>>>(ybuf_su, ybuf_sv, off_su, off_sv,
                                             edges_su, edges_sv, b2, HTb_su, HTb_sv, 32);
    }

    // ==== pooling (MFMA, A-amortized) + MLP ====
    {
        dim3 gr(NB / 16, PNK, 2);
        k_pool12<<<gr, 256, 0, stream>>>(su_len, sv_len, HTb_su, HTb_sv, pooled);
    }
    k_mlp<<<NB, 64, 0, stream>>>(pooled, fc1w, fc1b, fc2w, fc2b, fc3w, fc3b, out);
}

// Round 22
// 638.119 us; speedup vs baseline: 1.2342x; 1.0139x over previous
//
#include <hip/hip_runtime.h>
#include <hip/hip_bf16.h>

#define NN 100000
#define NE 3200000
#define NB 512
#define BINW 128                  // nodes per bin (bin = node >> 7)
#define NBINS 782                 // ceil(NN / 128); 782*128 = 100096
#define EPB 8192                  // edges per p1/p3 block
#define NBLK 391                  // ceil(NE / EPB)
#define PK 3200                   // pool k-chunk; 32*3200 = 102400 >= NN
#define PNK 32

typedef unsigned short ushort_t;
typedef unsigned int uint_t;
typedef unsigned char uchar_t;
typedef __attribute__((ext_vector_type(8))) short short8v;   // 8 bf16 (4 VGPRs)
typedef __attribute__((ext_vector_type(4))) float f32x4v;

static __device__ __forceinline__ short f2bf(float f) {
    __hip_bfloat16 h = __float2bfloat16(f);
    return *reinterpret_cast<short*>(&h);
}
static __device__ __forceinline__ float bf2f(ushort_t u) {
    return __uint_as_float(((uint_t)u) << 16);
}

// ---------------- p1: per-block bin-histograms (dst AND src), BOTH graphs ----------------
__global__ __launch_bounds__(256) void k_p1(const int* __restrict__ srcA,
                                            const int* __restrict__ dstA,
                                            const int* __restrict__ srcB,
                                            const int* __restrict__ dstB,
                                            int* __restrict__ cnt4,
                                            int* __restrict__ binTot) {
    __shared__ int hD[NBINS], hS[NBINS];
    int t = threadIdx.x, b = blockIdx.x;
    int g = (b >= NBLK) ? 1 : 0;
    int bb = b - g * NBLK;
    const int* src = g ? srcB : srcA;
    const int* dst = g ? dstB : dstA;
    int* cntD = cnt4 + (size_t)(2 * g)     * NBLK * NBINS;
    int* cntS = cnt4 + (size_t)(2 * g + 1) * NBLK * NBINS;
    int* btD  = binTot + (2 * g) * NBINS;
    int* btS  = binTot + (2 * g + 1) * NBINS;
    for (int i = t; i < NBINS; i += 256) { hD[i] = 0; hS[i] = 0; }
    __syncthreads();
    int base = bb * EPB;
#pragma unroll
    for (int i = 0; i < EPB / 1024; i++) {
        int idx = base + i * 1024 + t * 4;
        if (idx < NE) {  // NE%4==0 -> whole int4 valid
            int4 d4 = *(const int4*)(dst + idx);
            int4 s4 = *(const int4*)(src + idx);
            atomicAdd(&hD[d4.x >> 7], 1); atomicAdd(&hD[d4.y >> 7], 1);
            atomicAdd(&hD[d4.z >> 7], 1); atomicAdd(&hD[d4.w >> 7], 1);
            atomicAdd(&hS[s4.x >> 7], 1); atomicAdd(&hS[s4.y >> 7], 1);
            atomicAdd(&hS[s4.z >> 7], 1); atomicAdd(&hS[s4.w >> 7], 1);
        }
    }
    __syncthreads();
    for (int i = t; i < NBINS; i += 256) {
        int vD = hD[i]; cntD[(size_t)bb * NBINS + i] = vD; if (vD) atomicAdd(btD + i, vD);
        int vS = hS[i]; cntS[(size_t)bb * NBINS + i] = vS; if (vS) atomicAdd(btS + i, vS);
    }
}

// ---------------- scanA: exclusive scan of bin totals, 4 units ----------------
__global__ void k_scanA(const int* __restrict__ binTot, int* __restrict__ binBase,
                        int* __restrict__ off_su, int* __restrict__ off_sv) {
    __shared__ int s[NBINS];
    int u = blockIdx.x;  // 0=D_su 1=S_su 2=D_sv 3=S_sv
    const int* bt = binTot + u * NBINS;
    int* bb = binBase + u * (NBINS + 1);
    int t = threadIdx.x;
    for (int i = t; i < NBINS; i += 256) s[i] = bt[i];
    __syncthreads();
    if (t == 0) {
        int acc = 0;
        for (int i = 0; i < NBINS; i++) { int v = s[i]; s[i] = acc; acc += v; }
    }
    __syncthreads();
    for (int i = t; i < NBINS; i += 256) bb[i] = s[i];
    if (t == 0) bb[NBINS] = NE;
    if (t == 0 && u == 0) { off_su[NN] = NE; off_sv[NN] = NE; }
}

// ---------------- scanB: per-bin prefix over blocks, IN PLACE in cnt ----------------
__global__ void k_scanB(int* __restrict__ cnt4, const int* __restrict__ binBase) {
    __shared__ int s[NBLK];
    int u = blockIdx.x / NBINS, j = blockIdx.x % NBINS;
    int* cnt = cnt4 + (size_t)u * NBLK * NBINS;
    const int* bb = binBase + u * (NBINS + 1);
    int t = threadIdx.x;
    for (int i = t; i < NBLK; i += 256) s[i] = cnt[(size_t)i * NBINS + j];
    __syncthreads();
    if (t == 0) {
        int acc = bb[j];
        for (int i = 0; i < NBLK; i++) { int v = s[i]; s[i] = acc; acc += v; }
    }
    __syncthreads();
    for (int i = t; i < NBLK; i += 256) cnt[(size_t)i * NBINS + j] = s[i];
}

// ---------------- p3: dual scatter into bin order, BOTH graphs, packed payloads --------
// sortedD entry = src | (dst&127)<<20  (src<2^17; one int instead of int2: half traffic)
// sortedS entry = (uchar)(src&127)     (only the in-bin id is ever used: 1B instead of 4B)
__global__ __launch_bounds__(256) void k_p3(const int* __restrict__ srcA,
                                            const int* __restrict__ dstA,
                                            const int* __restrict__ srcB,
                                            const int* __restrict__ dstB,
                                            const int* __restrict__ cnt4,
                                            int* __restrict__ sdA, int* __restrict__ sdB,
                                            uchar_t* __restrict__ ssA,
                                            uchar_t* __restrict__ ssB) {
    __shared__ int curD[NBINS], curS[NBINS];
    int t = threadIdx.x, b = blockIdx.x;
    int g = (b >= NBLK) ? 1 : 0;
    int bb = b - g * NBLK;
    const int* src = g ? srcB : srcA;
    const int* dst = g ? dstB : dstA;
    const int* cntD = cnt4 + (size_t)(2 * g)     * NBLK * NBINS;
    const int* cntS = cnt4 + (size_t)(2 * g + 1) * NBLK * NBINS;
    int* sd = g ? sdB : sdA;
    uchar_t* ss = g ? ssB : ssA;
    for (int i = t; i < NBINS; i += 256) {
        curD[i] = cntD[(size_t)bb * NBINS + i];
        curS[i] = cntS[(size_t)bb * NBINS + i];
    }
    __syncthreads();
    int base = bb * EPB;
#pragma unroll
    for (int i = 0; i < EPB / 1024; i++) {
        int idx = base + i * 1024 + t * 4;
        if (idx < NE) {
            int4 s4 = *(const int4*)(src + idx);
            int4 d4 = *(const int4*)(dst + idx);
            int p;
            p = atomicAdd(&curD[d4.x >> 7], 1); sd[p] = s4.x | ((d4.x & 127) << 20);
            p = atomicAdd(&curD[d4.y >> 7], 1); sd[p] = s4.y | ((d4.y & 127) << 20);
            p = atomicAdd(&curD[d4.z >> 7], 1); sd[p] = s4.z | ((d4.z & 127) << 20);
            p = atomicAdd(&curD[d4.w >> 7], 1); sd[p] = s4.w | ((d4.w & 127) << 20);
            p = atomicAdd(&curS[s4.x >> 7], 1); ss[p] = (uchar_t)(s4.x & 127);
            p = atomicAdd(&curS[s4.y >> 7], 1); ss[p] = (uchar_t)(s4.y & 127);
            p = atomicAdd(&curS[s4.z >> 7], 1); ss[p] = (uchar_t)(s4.z & 127);
            p = atomicAdd(&curS[s4.w >> 7], 1); ss[p] = (uchar_t)(s4.w & 127);
        }
    }
}

// ---------------- p4: [0,2N) D counting-sort -> CSR per graph; [2N,4N) S hist ----------
__global__ __launch_bounds__(256) void k_p4(const int* __restrict__ sdA,
                                            const int* __restrict__ sdB,
                                            const uchar_t* __restrict__ ssA,
                                            const uchar_t* __restrict__ ssB,
                                            const int* __restrict__ binBase,
                                            int* __restrict__ offA, int* __restrict__ offB,
                                            int* __restrict__ edgesA,
                                            int* __restrict__ edgesB,
                                            int* __restrict__ csA, int* __restrict__ csB) {
    __shared__ int hist[BINW], pre[BINW], cur[BINW];
    int t = threadIdx.x;
    int u = blockIdx.x / NBINS, bin = blockIdx.x % NBINS;
    if (u < 2) {
        const int* sd = u ? sdB : sdA;
        const int* bb = binBase + (2 * u) * (NBINS + 1);
        int* off   = u ? offB : offA;
        int* edges = u ? edgesB : edgesA;
        if (t < BINW) hist[t] = 0;
        __syncthreads();
        int e0 = bb[bin], e1 = bb[bin + 1];
        for (int e = e0 + t; e < e1; e += 256)
            atomicAdd(&hist[sd[e] >> 20], 1);
        __syncthreads();
        if (t == 0) {
            int a = 0;
            for (int i = 0; i < BINW; i++) { pre[i] = a; a += hist[i]; }
        }
        __syncthreads();
        if (t < BINW) {
            cur[t] = pre[t];
            int node = bin * BINW + t;
            if (node < NN) off[node] = e0 + pre[t];
        }
        __syncthreads();
        for (int e = e0 + t; e < e1; e += 256) {
            int v = sd[e];
            int p = atomicAdd(&cur[v >> 20], 1);
            edges[e0 + p] = v & 0xFFFFF;
        }
    } else {
        const uchar_t* ss = (u == 3) ? ssB : ssA;
        const int* bb = binBase + (2 * (u - 2) + 1) * (NBINS + 1);
        int* cs = (u == 3) ? csB : csA;
        if (t < BINW) hist[t] = 0;
        __syncthreads();
        int e0 = bb[bin], e1 = bb[bin + 1];
        for (int e = e0 + t; e < e1; e += 256)
            atomicAdd(&hist[ss[e]], 1);
        __syncthreads();
        if (t < BINW) {
            int node = bin * BINW + t;
            if (node < NN) cs[node] = hist[t];
        }
    }
}

// ---------------- t1 (both graphs): y = (x*sn)@W1 (bf16) ----------------
__global__ __launch_bounds__(256) void k_t1(const float* __restrict__ xA,
                                            const float* __restrict__ xB,
                                            const float* __restrict__ W1,
                                            const int* __restrict__ csA,
                                            const int* __restrict__ csB,
                                            ushort_t* __restrict__ yA,
                                            ushort_t* __restrict__ yB) {
    __shared__ float sW[2048];
    __shared__ float sx[8 * 65];
    int g = blockIdx.y;
    const float* x = g ? xB : xA;
    const int* cnt_src = g ? csB : csA;
    ushort_t* y = g ? yB : yA;
    int t = threadIdx.x;
    int node0 = blockIdx.x * 8;
    for (int i = t; i < 2048; i += 256) sW[i] = W1[i];
    for (int i = t; i < 512; i += 256) {
        int r = i >> 6, k = i & 63;
        sx[r * 65 + k] = x[(size_t)(node0 + r) * 64 + k];
    }
    __syncthreads();
    int r = t >> 5, c = t & 31;
    int node = node0 + r;
    float sn = rsqrtf(fmaxf((float)cnt_src[node], 1.0f));
    float acc = 0.0f;
#pragma unroll
    for (int k = 0; k < 64; k++) acc += sx[r * 65 + k] * sW[k * 32 + c];
    acc *= sn;   // row scalar commutes with @W1
    y[(size_t)node * 32 + c] = (ushort_t)f2bf(acc);
}

// ---------------- t2 (both graphs): y2 = (HTb_rows(0..31)*sn)@W2 ----------------
__global__ __launch_bounds__(256) void k_t2(const ushort_t* __restrict__ HTbA,
                                            const ushort_t* __restrict__ HTbB,
                                            const float* __restrict__ W2,
                                            const int* __restrict__ csA,
                                            const int* __restrict__ csB,
                                            ushort_t* __restrict__ yA,
                                            ushort_t* __restrict__ yB) {
    __shared__ float sW[512];
    __shared__ float sx[16 * 33];
    int g = blockIdx.y;
    const ushort_t* HTb = g ? HTbB : HTbA;
    const int* cnt_src = g ? csB : csA;
    ushort_t* y2 = g ? yB : yA;
    int t = threadIdx.x;
    int node0 = blockIdx.x * 16;
    for (int i = t; i < 512; i += 256) sW[i] = W2[i];
    for (int i = t; i < 512; i += 256) {
        int r = i & 15, k = i >> 4;  // r fast -> coalesced over node dim
        sx[r * 33 + k] = bf2f(HTb[(size_t)k * NN + node0 + r]);
    }
    __syncthreads();
    int r = t >> 4, c = t & 15;
    int node = node0 + r;
    float sn = rsqrtf(fmaxf((float)cnt_src[node], 1.0f));
    float acc = 0.0f;
#pragma unroll
    for (int k = 0; k < 32; k++) acc += sx[r * 33 + k] * sW[k * 16 + c];
    acc *= sn;
    y2[(size_t)node * 16 + c] = (ushort_t)f2bf(acc);
}

// ---------------- CSR gather aggregation (both graphs), packed-uint y ----------------
template <int F, int RELU>
__global__ __launch_bounds__(256) void k_agg(
        const uint_t* __restrict__ yA, const uint_t* __restrict__ yB,
        const int* __restrict__ offA, const int* __restrict__ offB,
        const int* __restrict__ edgesA, const int* __restrict__ edgesB,
        const float* __restrict__ bias,
        ushort_t* __restrict__ HTbA, ushort_t* __restrict__ HTbB, int coloff) {
    constexpr int L = F / 2;
    constexpr int NPB = 256 / L;
    int gsel = blockIdx.y;
    const uint_t* y = gsel ? yB : yA;
    const int* off = gsel ? offB : offA;
    const int* edges = gsel ? edgesB : edgesA;
    ushort_t* HTb = gsel ? HTbB : HTbA;
    int t = threadIdx.x;
    int g = t / L, c2 = t % L;
    int node = blockIdx.x * NPB + g;
    int e0 = off[node], e1 = off[node + 1];
    int deg = e1 - e0;
    const int* srow = edges + e0;
    float a0 = 0.0f, a1 = 0.0f;
    int e = 0;
    for (; e + 3 < deg; e += 4) {
        int s0 = srow[e], s1 = srow[e + 1], s2 = srow[e + 2], s3 = srow[e + 3];
        uint_t u0 = y[(size_t)s0 * L + c2];
        uint_t u1 = y[(size_t)s1 * L + c2];
        uint_t u2 = y[(size_t)s2 * L + c2];
        uint_t u3 = y[(size_t)s3 * L + c2];
        a0 += __uint_as_float(u0 << 16) + __uint_as_float(u1 << 16)
            + __uint_as_float(u2 << 16) + __uint_as_float(u3 << 16);
        a1 += __uint_as_float(u0 & 0xFFFF0000u) + __uint_as_float(u1 & 0xFFFF0000u)
            + __uint_as_float(u2 & 0xFFFF0000u) + __uint_as_float(u3 & 0xFFFF0000u);
    }
    for (; e < deg; e++) {
        uint_t u = y[(size_t)srow[e] * L + c2];
        a0 += __uint_as_float(u << 16);
        a1 += __uint_as_float(u & 0xFFFF0000u);
    }
    float dn = rsqrtf(fmaxf((float)deg, 1.0f));
    float v0 = a0 * dn + bias[2 * c2];
    float v1 = a1 * dn + bias[2 * c2 + 1];
    if (RELU) { v0 = fmaxf(v0, 0.0f); v1 = fmaxf(v1, 0.0f); }
    HTb[(size_t)(coloff + 2 * c2) * NN + node] = (ushort_t)f2bf(v0);
    HTb[(size_t)(coloff + 2 * c2 + 1) * NN + node] = (ushort_t)f2bf(v1);
}

// ---------------- pooling v15: MFMA, 32-graph x 48-col wave tile ----------------
// r21 CONFIRMED the vmem-rate theory (A-amortized tile: 208->152us, FETCH 430->284MB).
// Push harder: 32 graphs/wave (two A-row groups share the same 6 B loads) ->
// 14 vmem / 12 MFMA (vs 10/6). VGPR ~95 (acc 24 + A 32 + B 24 + addr), 4 waves/SIMD.
// Grid bx=16, PNK=32 -> 1024 blocks (B re-fetch halves vs r21; HTb is L3-resident).
// Coverage (PK=3200=12.5x256): w0/w1 get 13 halfsteps, w2/w3 get 12; guarded tail covers
// the last 32-elem fragment of the final chunk (8|NN, 8|kend -> seg valid iff kb<kend).
// Frag layouts (guide §3, m89-verified): A lane l -> row l&15, k=(l>>4)*8+i; B lane l ->
// col l&15, same k; C/D lane l reg r -> row (l>>4)*4+r, col l&15.
__global__ __launch_bounds__(256) void k_pool13(
        const float* __restrict__ lenA, const float* __restrict__ lenB,
        const ushort_t* __restrict__ HTbA, const ushort_t* __restrict__ HTbB,
        float* __restrict__ pooled) {
    __shared__ float red[3][6][64][4];   // [wave-1][gg*3+ctile][lane][reg]
    const int mat = blockIdx.z;
    const float* __restrict__ len = mat ? lenB : lenA;
    const ushort_t* __restrict__ HTb = mat ? HTbB : HTbA;
    const int colbase = mat ? 48 : 0;
    const int b0 = blockIdx.x * 32;
    const int w = threadIdx.x >> 6;   // k-partner 0..3
    const int l = threadIdx.x & 63;
    const int rc = l & 15;
    const int seg = l >> 4;           // 0..3

    const int kc0 = blockIdx.y * PK;
    const int kend = (kc0 + PK < NN) ? (kc0 + PK) : NN;
    const float* lrow0 = len + (size_t)(b0 + rc) * NN;
    const float* lrow1 = len + (size_t)(b0 + 16 + rc) * NN;
    const ushort_t* h0 = HTb + (size_t)(0 * 16 + rc) * NN;
    const ushort_t* h1 = HTb + (size_t)(1 * 16 + rc) * NN;
    const ushort_t* h2 = HTb + (size_t)(2 * 16 + rc) * NN;

    f32x4v ac00 = {0, 0, 0, 0}, ac01 = {0, 0, 0, 0}, ac02 = {0, 0, 0, 0};
    f32x4v ac10 = {0, 0, 0, 0}, ac11 = {0, 0, 0, 0}, ac12 = {0, 0, 0, 0};

    const int kw0 = kc0 + w * 64;     // this wave's first halfstep base (stride 256)
    const int lb0 = kw0 + seg * 8;
    int avail = kend - kw0;
    int T = (avail >= 64) ? ((avail - 64) >> 8) + 1 : 0;  // full 64-k halfsteps

    for (int t = 0; t < T; t++) {
        int kb = lb0 + t * 256;
        // A group 0 and 1: load once each, reuse for 3 col tiles
        f32x4v q0 = *(const f32x4v*)(lrow0 + kb);
        f32x4v q1 = *(const f32x4v*)(lrow0 + kb + 4);
        f32x4v q2 = *(const f32x4v*)(lrow0 + kb + 32);
        f32x4v q3 = *(const f32x4v*)(lrow0 + kb + 36);
        f32x4v q4 = *(const f32x4v*)(lrow1 + kb);
        f32x4v q5 = *(const f32x4v*)(lrow1 + kb + 4);
        f32x4v q6 = *(const f32x4v*)(lrow1 + kb + 32);
        f32x4v q7 = *(const f32x4v*)(lrow1 + kb + 36);
        short8v b00 = *(const short8v*)(h0 + kb);
        short8v b01 = *(const short8v*)(h0 + kb + 32);
        short8v b10 = *(const short8v*)(h1 + kb);
        short8v b11 = *(const short8v*)(h1 + kb + 32);
        short8v b20 = *(const short8v*)(h2 + kb);
        short8v b21 = *(const short8v*)(h2 + kb + 32);
        short8v A0, A1, A2, A3;
        A0[0] = f2bf(q0.x); A0[1] = f2bf(q0.y); A0[2] = f2bf(q0.z); A0[3] = f2bf(q0.w);
        A0[4] = f2bf(q1.x); A0[5] = f2bf(q1.y); A0[6] = f2bf(q1.z); A0[7] = f2bf(q1.w);
        A1[0] = f2bf(q2.x); A1[1] = f2bf(q2.y); A1[2] = f2bf(q2.z); A1[3] = f2bf(q2.w);
        A1[4] = f2bf(q3.x); A1[5] = f2bf(q3.y); A1[6] = f2bf(q3.z); A1[7] = f2bf(q3.w);
        A2[0] = f2bf(q4.x); A2[1] = f2bf(q4.y); A2[2] = f2bf(q4.z); A2[3] = f2bf(q4.w);
        A2[4] = f2bf(q5.x); A2[5] = f2bf(q5.y); A2[6] = f2bf(q5.z); A2[7] = f2bf(q5.w);
        A3[0] = f2bf(q6.x); A3[1] = f2bf(q6.y); A3[2] = f2bf(q6.z); A3[3] = f2bf(q6.w);
        A3[4] = f2bf(q7.x); A3[5] = f2bf(q7.y); A3[6] = f2bf(q7.z); A3[7] = f2bf(q7.w);
        ac00 = __builtin_amdgcn_mfma_f32_16x16x32_bf16(A0, b00, ac00, 0, 0, 0);
        ac00 = __builtin_amdgcn_mfma_f32_16x16x32_bf16(A1, b01, ac00, 0, 0, 0);
        ac01 = __builtin_amdgcn_mfma_f32_16x16x32_bf16(A0, b10, ac01, 0, 0, 0);
        ac01 = __builtin_amdgcn_mfma_f32_16x16x32_bf16(A1, b11, ac01, 0, 0, 0);
        ac02 = __builtin_amdgcn_mfma_f32_16x16x32_bf16(A0, b20, ac02, 0, 0, 0);
        ac02 = __builtin_amdgcn_mfma_f32_16x16x32_bf16(A1, b21, ac02, 0, 0, 0);
        ac10 = __builtin_amdgcn_mfma_f32_16x16x32_bf16(A2, b00, ac10, 0, 0, 0);
        ac10 = __builtin_amdgcn_mfma_f32_16x16x32_bf16(A3, b01, ac10, 0, 0, 0);
        ac11 = __builtin_amdgcn_mfma_f32_16x16x32_bf16(A2, b10, ac11, 0, 0, 0);
        ac11 = __builtin_amdgcn_mfma_f32_16x16x32_bf16(A3, b11, ac11, 0, 0, 0);
        ac12 = __builtin_amdgcn_mfma_f32_16x16x32_bf16(A2, b20, ac12, 0, 0, 0);
        ac12 = __builtin_amdgcn_mfma_f32_16x16x32_bf16(A3, b21, ac12, 0, 0, 0);
    }

    // guarded tail halfstep (remaining < 64 k of the final chunk)
    int kt = kw0 + T * 256;
    if (kt < kend) {
#pragma unroll
        for (int h = 0; h < 2; h++) {
            int kb = kt + h * 32 + seg * 8;
            short8v a0 = (short8v)0, a1 = (short8v)0;
            short8v v0 = (short8v)0, v1 = (short8v)0, v2 = (short8v)0;
            if (kb < kend) {
                f32x4v q0 = *(const f32x4v*)(lrow0 + kb);
                f32x4v q1 = *(const f32x4v*)(lrow0 + kb + 4);
                f32x4v q2 = *(const f32x4v*)(lrow1 + kb);
                f32x4v q3 = *(const f32x4v*)(lrow1 + kb + 4);
                a0[0] = f2bf(q0.x); a0[1] = f2bf(q0.y); a0[2] = f2bf(q0.z); a0[3] = f2bf(q0.w);
                a0[4] = f2bf(q1.x); a0[5] = f2bf(q1.y); a0[6] = f2bf(q1.z); a0[7] = f2bf(q1.w);
                a1[0] = f2bf(q2.x); a1[1] = f2bf(q2.y); a1[2] = f2bf(q2.z); a1[3] = f2bf(q2.w);
                a1[4] = f2bf(q3.x); a1[5] = f2bf(q3.y); a1[6] = f2bf(q3.z); a1[7] = f2bf(q3.w);
                v0 = *(const short8v*)(h0 + kb);
                v1 = *(const short8v*)(h1 + kb);
                v2 = *(const short8v*)(h2 + kb);
            }
            ac00 = __builtin_amdgcn_mfma_f32_16x16x32_bf16(a0, v0, ac00, 0, 0, 0);
            ac01 = __builtin_amdgcn_mfma_f32_16x16x32_bf16(a0, v1, ac01, 0, 0, 0);
            ac02 = __builtin_amdgcn_mfma_f32_16x16x32_bf16(a0, v2, ac02, 0, 0, 0);
            ac10 = __builtin_amdgcn_mfma_f32_16x16x32_bf16(a1, v0, ac10, 0, 0, 0);
            ac11 = __builtin_amdgcn_mfma_f32_16x16x32_bf16(a1, v1, ac11, 0, 0, 0);
            ac12 = __builtin_amdgcn_mfma_f32_16x16x32_bf16(a1, v2, ac12, 0, 0, 0);
        }
    }

    // 4-way k-partner reduce via LDS; wave 0 finishes with atomics
    if (w > 0) {
        *(f32x4v*)&red[w - 1][0][l][0] = ac00;
        *(f32x4v*)&red[w - 1][1][l][0] = ac01;
        *(f32x4v*)&red[w - 1][2][l][0] = ac02;
        *(f32x4v*)&red[w - 1][3][l][0] = ac10;
        *(f32x4v*)&red[w - 1][4][l][0] = ac11;
        *(f32x4v*)&red[w - 1][5][l][0] = ac12;
    }
    __syncthreads();
    if (w == 0) {
        f32x4v s0 = ac00, s1 = ac01, s2 = ac02, s3 = ac10, s4 = ac11, s5 = ac12;
#pragma unroll
        for (int j = 0; j < 3; j++) {
            s0 += *(const f32x4v*)&red[j][0][l][0];
            s1 += *(const f32x4v*)&red[j][1][l][0];
            s2 += *(const f32x4v*)&red[j][2][l][0];
            s3 += *(const f32x4v*)&red[j][3][l][0];
            s4 += *(const f32x4v*)&red[j][4][l][0];
            s5 += *(const f32x4v*)&red[j][5][l][0];
        }
#pragma unroll
        for (int r = 0; r < 4; r++) {
            int row0 = (b0 + seg * 4 + r) * 96 + colbase;
            int row1 = (b0 + 16 + seg * 4 + r) * 96 + colbase;
            atomicAdd(&pooled[row0 + 0 * 16 + rc], s0[r]);
            atomicAdd(&pooled[row0 + 1 * 16 + rc], s1[r]);
            atomicAdd(&pooled[row0 + 2 * 16 + rc], s2[r]);
            atomicAdd(&pooled[row1 + 0 * 16 + rc], s3[r]);
            atomicAdd(&pooled[row1 + 1 * 16 + rc], s4[r]);
            atomicAdd(&pooled[row1 + 2 * 16 + rc], s5[r]);
        }
    }
}

// ---------------- MLP head ----------------
__global__ void k_mlp(const float* __restrict__ pooled,
                      const float* __restrict__ fc1w, const float* __restrict__ fc1b,
                      const float* __restrict__ fc2w, const float* __restrict__ fc2b,
                      const float* __restrict__ fc3w, const float* __restrict__ fc3b,
                      float* __restrict__ out) {
    __shared__ float srow[96];
    __shared__ float sh[64];
    __shared__ float sh2[16];
    int b = blockIdx.x, t = threadIdx.x; // 64 threads
    srow[t] = pooled[b * 96 + t];
    if (t < 32) srow[64 + t] = pooled[b * 96 + 64 + t];
    __syncthreads();
    float acc = fc1b[t];
    for (int k = 0; k < 96; k++) acc += srow[k] * fc1w[k * 64 + t];
    sh[t] = fmaxf(acc, 0.0f);
    __syncthreads();
    if (t < 16) {
        float a2 = fc2b[t];
        for (int k = 0; k < 64; k++) a2 += sh[k] * fc2w[k * 16 + t];
        sh2[t] = fmaxf(a2, 0.0f);
    }
    __syncthreads();
    if (t == 0) {
        float a3 = fc3b[0];
        for (int k = 0; k < 16; k++) a3 += sh2[k] * fc3w[k];
        out[b] = a3;
    }
}

extern "C" void kernel_launch(void* const* d_in, const int* in_sizes, int n_in,
                              void* d_out, int out_size, void* d_ws, size_t ws_size,
                              hipStream_t stream) {
    const float* solute_x  = (const float*)d_in[0];
    const float* solvent_x = (const float*)d_in[1];
    const float* su_len    = (const float*)d_in[2];
    const float* sv_len    = (const float*)d_in[3];
    const int*   su_src    = (const int*)d_in[4];
    const int*   su_dst    = (const int*)d_in[5];
    const int*   sv_src    = (const int*)d_in[6];
    const int*   sv_dst    = (const int*)d_in[7];
    const float* W1  = (const float*)d_in[8];
    const float* b1  = (const float*)d_in[9];
    const float* W2  = (const float*)d_in[10];
    const float* b2  = (const float*)d_in[11];
    const float* fc1w = (const float*)d_in[12];
    const float* fc1b = (const float*)d_in[13];
    const float* fc2w = (const float*)d_in[14];
    const float* fc2b = (const float*)d_in[15];
    const float* fc3w = (const float*)d_in[16];
    const float* fc3b = (const float*)d_in[17];
    float* out = (float*)d_out;

    // ---- arena (4B words), total ~64.4 MB ----
    char* ws = (char*)d_ws;
    size_t o = 0;
    auto alloc = [&](size_t elems) { void* p = ws + o * 4; o += elems; return p; };
    int* cnt4     = (int*)alloc((size_t)4 * NBLK * NBINS);  // [D_su][S_su][D_sv][S_sv]
    int* binTot   = (int*)alloc(4 * NBINS);
    int* binBase  = (int*)alloc(4 * (NBINS + 1));
    int* off_su   = (int*)alloc(NN + 1);
    int* off_sv   = (int*)alloc(NN + 1);
    int* csrc_su  = (int*)alloc(NN);
    int* csrc_sv  = (int*)alloc(NN);
    float* pooled = (float*)alloc(NB * 96);
    int* edges_su = (int*)alloc(NE);
    int* edges_sv = (int*)alloc(NE);
    o = (o + 1) & ~(size_t)1;                 // 8B align
    // union region X (32 MB):
    //   build:   sdA int NE (12.8) | sdB int NE (12.8) | ssA uchar NE (3.2) | ssB (3.2)
    //   compute: ybuf_su 6.4 | ybuf_sv 6.4 | HTb_su 9.6 | HTb_sv 9.6
    char* X = ws + o * 4;
    int*      sdA     = (int*)X;
    int*      sdB     = (int*)(X + (size_t)NE * 4);
    uchar_t*  ssA     = (uchar_t*)(X + (size_t)NE * 8);
    uchar_t*  ssB     = (uchar_t*)(X + (size_t)NE * 9);
    uint_t*   ybuf_su = (uint_t*)X;
    uint_t*   ybuf_sv = (uint_t*)(X + (size_t)NN * 64);
    ushort_t* HTb_su  = (ushort_t*)(X + (size_t)NN * 128);
    ushort_t* HTb_sv  = (ushort_t*)(X + (size_t)NN * 128 + (size_t)NN * 96);

    hipMemsetAsync(binTot, 0, 4 * NBINS * 4, stream);
    hipMemsetAsync(pooled, 0, NB * 96 * 4, stream);

    // ==== phase 1: sort-based CSR build, both graphs, merged launches ====
    k_p1<<<2 * NBLK, 256, 0, stream>>>(su_src, su_dst, sv_src, sv_dst, cnt4, binTot);
    k_scanA<<<4, 256, 0, stream>>>(binTot, binBase, off_su, off_sv);
    k_scanB<<<4 * NBINS, 256, 0, stream>>>(cnt4, binBase);
    k_p3<<<2 * NBLK, 256, 0, stream>>>(su_src, su_dst, sv_src, sv_dst, cnt4,
                                       sdA, sdB, ssA, ssB);
    k_p4<<<4 * NBINS, 256, 0, stream>>>(sdA, sdB, ssA, ssB, binBase,
                                        off_su, off_sv, edges_su, edges_sv,
                                        csrc_su, csrc_sv);

    // ==== phase 2: GCN layers, both graphs per launch (sorted buffers now dead) ====
    {
        dim3 g1(NN / 8, 2);
        k_t1<<<g1, 256, 0, stream>>>(solute_x, solvent_x, W1, csrc_su, csrc_sv,
                                     (ushort_t*)ybuf_su, (ushort_t*)ybuf_sv);
        dim3 g2(NN / 16, 2);
        k_agg<32, 1><<<g2, 256, 0, stream>>>(ybuf_su, ybuf_sv, off_su, off_sv,
                                             edges_su, edges_sv, b1, HTb_su, HTb_sv, 0);
        k_t2<<<g2, 256, 0, stream>>>(HTb_su, HTb_sv, W2, csrc_su, csrc_sv,
                                     (ushort_t*)ybuf_su, (ushort_t*)ybuf_sv);
        dim3 g3(NN / 32, 2);
        k_agg<16, 0><<<g3, 256, 0, stream>>>(ybuf_su, ybuf_sv, off_su, off_sv,
                                             edges_su, edges_sv, b2, HTb_su, HTb_sv, 32);
    }

    // ==== pooling (MFMA, 32-graph tile) + MLP ====
    {
        dim3 gr(NB / 32, PNK, 2);
        k_pool13<<<gr, 256, 0, stream>>>(su_len, sv_len, HTb_su, HTb_sv, pooled);
    }
    k_mlp<<<NB, 64, 0, stream>>>(pooled, fc1w, fc1b, fc2w, fc2b, fc3w, fc3b, out);
}